// Round 1
// baseline (665.231 us; speedup 1.0000x reference)
//
#include <hip/hip_runtime.h>
#include <math.h>

#define DN 16
#define DNZ 16
#define DOUT 8
#define DH 32
#define DB 16384
#define RINV 10.0f

// ---- LDS layout offsets (floats) ----
#define O_Wf1   0       // 512
#define O_bf1   512     // 32
#define O_Wf2   544     // 512
#define O_Wh1   1056    // 512
#define O_bh1   1568    // 32
#define O_Wh2   1600    // 256
#define O_WT1   1856    // 512
#define O_bT1   2368    // 32
#define O_WT2   2400    // 512
#define O_Wtau1 2912    // 512
#define O_btau1 3424    // 32
#define O_Wtau2 3456    // 512
#define O_Wpsi1 3968    // 768
#define O_bpsi1 4736    // 32
#define O_Wpsi2 4768    // 512
#define O_WP    5280    // 256
#define LDS_FLOATS 5536

template<int M, int K>
__device__ __forceinline__ void mv(const float* __restrict__ W, const float* __restrict__ v,
                                   float* __restrict__ o) {
#pragma unroll
  for (int i = 0; i < M; ++i) {
    float a = 0.f;
#pragma unroll
    for (int j = 0; j < K; ++j) a = fmaf(W[i * K + j], v[j], a);
    o[i] = a;
  }
}

// two matvecs sharing the same W (read W once)
template<int M, int K>
__device__ __forceinline__ void mv2(const float* __restrict__ W,
                                    const float* __restrict__ va, const float* __restrict__ vb,
                                    float* __restrict__ oa, float* __restrict__ ob) {
#pragma unroll
  for (int i = 0; i < M; ++i) {
    float a = 0.f, b = 0.f;
#pragma unroll
    for (int j = 0; j < K; ++j) {
      float w = W[i * K + j];
      a = fmaf(w, va[j], a);
      b = fmaf(w, vb[j], b);
    }
    oa[i] = a;
    ob[i] = b;
  }
}

__device__ __forceinline__ float ftanh(float v) { return tanhf(v); }

__global__ __launch_bounds__(64, 1) void loss_kernel(
    const float* __restrict__ x_batch, const float* __restrict__ e_batch,
    const float* __restrict__ Wf1, const float* __restrict__ bf1, const float* __restrict__ Wf2,
    const float* __restrict__ Wh1, const float* __restrict__ bh1, const float* __restrict__ Wh2,
    const float* __restrict__ WT1, const float* __restrict__ bT1, const float* __restrict__ WT2,
    const float* __restrict__ Wtau1, const float* __restrict__ btau1, const float* __restrict__ Wtau2,
    const float* __restrict__ Wpsi1, const float* __restrict__ bpsi1, const float* __restrict__ Wpsi2,
    const float* __restrict__ WP,
    float* __restrict__ out) {
  __shared__ float sW[LDS_FLOATS];
  const int tid = threadIdx.x;

  // ---- cooperative weight staging into LDS ----
  {
    const float* srcs[16] = {Wf1, bf1, Wf2, Wh1, bh1, Wh2, WT1, bT1, WT2,
                             Wtau1, btau1, Wtau2, Wpsi1, bpsi1, Wpsi2, WP};
    const int offs[16] = {O_Wf1, O_bf1, O_Wf2, O_Wh1, O_bh1, O_Wh2, O_WT1, O_bT1, O_WT2,
                          O_Wtau1, O_btau1, O_Wtau2, O_Wpsi1, O_bpsi1, O_Wpsi2, O_WP};
    const int ns[16] = {512, 32, 512, 512, 32, 256, 512, 32, 512,
                        512, 32, 512, 768, 32, 512, 256};
    for (int p = 0; p < 16; ++p) {
      for (int i = tid; i < ns[p]; i += 64) sW[offs[p] + i] = srcs[p][i];
    }
  }
  __syncthreads();

  const float* sWf1 = sW + O_Wf1;
  const float* sbf1 = sW + O_bf1;
  const float* sWf2 = sW + O_Wf2;
  const float* sWh1 = sW + O_Wh1;
  const float* sbh1 = sW + O_bh1;
  const float* sWh2 = sW + O_Wh2;
  const float* sWT1 = sW + O_WT1;
  const float* sbT1 = sW + O_bT1;
  const float* sWT2 = sW + O_WT2;
  const float* sWtau1 = sW + O_Wtau1;
  const float* sbtau1 = sW + O_btau1;
  const float* sWtau2 = sW + O_Wtau2;
  const float* sWpsi1 = sW + O_Wpsi1;
  const float* sbpsi1 = sW + O_bpsi1;
  const float* sWpsi2 = sW + O_Wpsi2;
  const float* sWP = sW + O_WP;

  const int sidx = blockIdx.x * 64 + tid;

  // ---- load sample (coalesced via float4) ----
  float x[DN], e[DNZ];
  {
    const float4* xp = reinterpret_cast<const float4*>(x_batch + (size_t)sidx * DN);
    const float4* ep = reinterpret_cast<const float4*>(e_batch + (size_t)sidx * DNZ);
#pragma unroll
    for (int q = 0; q < 4; ++q) {
      float4 vx = xp[q], ve = ep[q];
      x[4 * q + 0] = vx.x; x[4 * q + 1] = vx.y; x[4 * q + 2] = vx.z; x[4 * q + 3] = vx.w;
      e[4 * q + 0] = ve.x; e[4 * q + 1] = ve.y; e[4 * q + 2] = ve.z; e[4 * q + 3] = ve.w;
    }
  }

  float t32[DH];

  // ---- z = T(x) + e ----
  mv<DH, DN>(sWT1, x, t32);
#pragma unroll
  for (int k = 0; k < DH; ++k) t32[k] = ftanh(t32[k] + sbT1[k]);
  float z[DNZ];
  mv<DNZ, DH>(sWT2, t32, z);
#pragma unroll
  for (int j = 0; j < DNZ; ++j) z[j] += e[j];

  // ---- x_hat = tau(z) ----
  mv<DH, DNZ>(sWtau1, z, t32);
#pragma unroll
  for (int k = 0; k < DH; ++k) t32[k] = ftanh(t32[k] + sbtau1[k]);
  float xh[DN];
  mv<DN, DH>(sWtau2, t32, xh);
  float diff[DN];
#pragma unroll
  for (int n = 0; n < DN; ++n) diff[n] = x[n] - xh[n];

  // ---- Tx = T(x_hat) ----
  mv<DH, DN>(sWT1, xh, t32);
#pragma unroll
  for (int k = 0; k < DH; ++k) t32[k] = ftanh(t32[k] + sbT1[k]);
  float Tx[DNZ];
  mv<DNZ, DH>(sWT2, t32, Tx);

  // ---- h stage: y_hat and dth ----
  float dth[DH];
  mv<DH, DN>(sWh1, xh, dth);
#pragma unroll
  for (int k = 0; k < DH; ++k) dth[k] = ftanh(dth[k] + sbh1[k]);  // th
  float yh[DOUT];
  mv<DOUT, DH>(sWh2, dth, yh);
#pragma unroll
  for (int k = 0; k < DH; ++k) dth[k] = 1.f - dth[k] * dth[k];  // 1-th^2

  // ---- psi stage: phi and dtp ----
  float cat[DNZ + DOUT];
#pragma unroll
  for (int j = 0; j < DNZ; ++j) cat[j] = Tx[j];
#pragma unroll
  for (int o = 0; o < DOUT; ++o) cat[DNZ + o] = yh[o];
  float dtp[DH];
  mv<DH, DNZ + DOUT>(sWpsi1, cat, dtp);
#pragma unroll
  for (int k = 0; k < DH; ++k) dtp[k] = ftanh(dtp[k] + sbpsi1[k]);  // tp
  float phi[DNZ];
  mv<DNZ, DH>(sWpsi2, dtp, phi);
#pragma unroll
  for (int k = 0; k < DH; ++k) dtp[k] = 1.f - dtp[k] * dtp[k];

  // ---- tau at Tx: dtt, Htau coeffs; v1 = Wtau1 @ e ----
  float tt[DH];
  mv<DH, DNZ>(sWtau1, Tx, tt);
#pragma unroll
  for (int k = 0; k < DH; ++k) tt[k] = ftanh(tt[k] + sbtau1[k]);
  float wphi[DH], v1[DH];
  mv2<DH, DNZ>(sWtau1, phi, e, wphi, v1);
  float cvec[DH], dv1[DH];
#pragma unroll
  for (int k = 0; k < DH; ++k) {
    float d = 1.f - tt[k] * tt[k];
    float c = -2.f * tt[k] * d * wphi[k];
    cvec[k] = c * v1[k];   // for Htau term
    dv1[k] = d * v1[k];    // for Jtau @ e
    tt[k] = d;             // now dtt
  }
  float t2e[DN], jtau_e[DN];
  mv2<DN, DH>(sWtau2, cvec, dv1, t2e, jtau_e);  // t2e = Htau-term @ e

  // ---- jphi_e = Jphi @ e;  t2e += Jtau @ jphi_e ----
  float q32[DH];
#pragma unroll
  for (int k = 0; k < DH; ++k) {
    float a = 0.f;
#pragma unroll
    for (int j = 0; j < DNZ; ++j) a = fmaf(sWpsi1[k * (DNZ + DOUT) + j], e[j], a);
    q32[k] = dtp[k] * a;
  }
  float jphi_e[DNZ];
  mv<DNZ, DH>(sWpsi2, q32, jphi_e);
  mv<DH, DNZ>(sWtau1, jphi_e, q32);
#pragma unroll
  for (int k = 0; k < DH; ++k) q32[k] *= tt[k];  // dtt
  float tmp16[DN];
  mv<DN, DH>(sWtau2, q32, tmp16);
#pragma unroll
  for (int n = 0; n < DN; ++n) t2e[n] += tmp16[n];

  // ---- t2e -= Jf @ jtau_e ----
  float tf[DH], g32[DH];
  mv2<DH, DN>(sWf1, xh, jtau_e, tf, g32);
#pragma unroll
  for (int k = 0; k < DH; ++k) {
    float t = ftanh(tf[k] + sbf1[k]);
    g32[k] *= (1.f - t * t);
  }
  mv<DN, DH>(sWf2, g32, tmp16);
#pragma unroll
  for (int n = 0; n < DN; ++n) t2e[n] -= tmp16[n];

  // ---- term1 = P_inv @ (Jh^T @ ((Jh @ diff) / R)) ----
  float w32[DH];
  mv<DH, DN>(sWh1, diff, w32);
#pragma unroll
  for (int k = 0; k < DH; ++k) w32[k] *= dth[k];
  float w8[DOUT];
  mv<DOUT, DH>(sWh2, w32, w8);
#pragma unroll
  for (int o = 0; o < DOUT; ++o) w8[o] *= RINV;
  // a32 = dth ∘ (Wh2^T @ w8)
  float a32[DH];
#pragma unroll
  for (int k = 0; k < DH; ++k) {
    float a = 0.f;
#pragma unroll
    for (int o = 0; o < DOUT; ++o) a = fmaf(sWh2[o * DH + k], w8[o], a);
    a32[k] = a * dth[k];
  }
  // u = Wh1^T @ a32
  float u[DN];
#pragma unroll
  for (int n = 0; n < DN; ++n) {
    float a = 0.f;
#pragma unroll
    for (int k = 0; k < DH; ++k) a = fmaf(sWh1[k * DN + n], a32[k], a);
    u[n] = a;
  }
  // s = tanh(WP @ xh); term1 = u + s*(s·u)
  float sv[DN];
  mv<DN, DN>(sWP, xh, sv);
#pragma unroll
  for (int n = 0; n < DN; ++n) sv[n] = ftanh(sv[n]);
  float sdot = 0.f;
#pragma unroll
  for (int n = 0; n < DN; ++n) sdot = fmaf(sv[n], u[n], sdot);

  float ss = 0.f;
#pragma unroll
  for (int n = 0; n < DN; ++n) {
    float t1 = u[n] + sv[n] * sdot;
    float r = t1 - t2e[n];
    ss = fmaf(r, r, ss);
  }
  float loss = sqrtf(ss);

  // ---- wave(=block) reduction + one atomic per block ----
#pragma unroll
  for (int off = 32; off >= 1; off >>= 1) loss += __shfl_down(loss, off);
  if (tid == 0) atomicAdd(out, loss * (1.0f / (float)DB));
}

extern "C" void kernel_launch(void* const* d_in, const int* in_sizes, int n_in,
                              void* d_out, int out_size, void* d_ws, size_t ws_size,
                              hipStream_t stream) {
  const float* x_batch = (const float*)d_in[0];
  const float* e_batch = (const float*)d_in[1];
  const float* Wf1 = (const float*)d_in[2];
  const float* bf1 = (const float*)d_in[3];
  const float* Wf2 = (const float*)d_in[4];
  const float* Wh1 = (const float*)d_in[5];
  const float* bh1 = (const float*)d_in[6];
  const float* Wh2 = (const float*)d_in[7];
  const float* WT1 = (const float*)d_in[8];
  const float* bT1 = (const float*)d_in[9];
  const float* WT2 = (const float*)d_in[10];
  const float* Wtau1 = (const float*)d_in[11];
  const float* btau1 = (const float*)d_in[12];
  const float* Wtau2 = (const float*)d_in[13];
  const float* Wpsi1 = (const float*)d_in[14];
  const float* bpsi1 = (const float*)d_in[15];
  const float* Wpsi2 = (const float*)d_in[16];
  const float* WP = (const float*)d_in[17];

  hipMemsetAsync(d_out, 0, sizeof(float), stream);
  loss_kernel<<<DB / 64, 64, 0, stream>>>(
      x_batch, e_batch, Wf1, bf1, Wf2, Wh1, bh1, Wh2, WT1, bT1, WT2,
      Wtau1, btau1, Wtau2, Wpsi1, bpsi1, Wpsi2, WP, (float*)d_out);
}

// Round 2
// 195.166 us; speedup vs baseline: 3.4085x; 3.4085x over previous
//
#include <hip/hip_runtime.h>
#include <math.h>

#define DN 16
#define DNZ 16
#define DOUT 8
#define DH 32
#define DB 16384
#define RINV 10.0f

// ---- LDS layout offsets (floats) ----
#define O_Wf1   0       // 512
#define O_bf1   512     // 32
#define O_Wf2   544     // 512
#define O_Wh1   1056    // 512
#define O_bh1   1568    // 32
#define O_Wh2   1600    // 256
#define O_WT1   1856    // 512
#define O_bT1   2368    // 32
#define O_WT2   2400    // 512
#define O_Wtau1 2912    // 512
#define O_btau1 3424    // 32
#define O_Wtau2 3456    // 512
#define O_Wpsi1 3968    // 768
#define O_bpsi1 4736    // 32
#define O_Wpsi2 4768    // 512
#define O_WP    5280    // 256
#define LDS_FLOATS 5536

template<int M, int K>
__device__ __forceinline__ void mv(const float* __restrict__ W, const float* __restrict__ v,
                                   float* __restrict__ o) {
#pragma unroll
  for (int i = 0; i < M; ++i) {
    float a = 0.f;
#pragma unroll
    for (int j = 0; j < K; ++j) a = fmaf(W[i * K + j], v[j], a);
    o[i] = a;
  }
}

// tanh(x) = 1 - 2/(1+exp(2x));  exp(2x) = exp2(x * 2*log2(e))
__device__ __forceinline__ float ftanh(float v) {
  float ex = __builtin_amdgcn_exp2f(v * 2.885390081777926815f);
  float r = __builtin_amdgcn_rcpf(1.0f + ex);
  return fmaf(-2.0f, r, 1.0f);
}

__global__ __launch_bounds__(64, 1) void loss_kernel(
    const float* __restrict__ x_batch, const float* __restrict__ e_batch,
    const float* __restrict__ Wf1, const float* __restrict__ bf1, const float* __restrict__ Wf2,
    const float* __restrict__ Wh1, const float* __restrict__ bh1, const float* __restrict__ Wh2,
    const float* __restrict__ WT1, const float* __restrict__ bT1, const float* __restrict__ WT2,
    const float* __restrict__ Wtau1, const float* __restrict__ btau1, const float* __restrict__ Wtau2,
    const float* __restrict__ Wpsi1, const float* __restrict__ bpsi1, const float* __restrict__ Wpsi2,
    const float* __restrict__ WP,
    float* __restrict__ out) {
  __shared__ float sW[LDS_FLOATS];
  const int tid = threadIdx.x;

  // ---- cooperative weight staging into LDS (no pointer arrays -> no scratch) ----
  {
#pragma unroll
    for (int r = 0; r < 8; ++r) sW[O_Wf1 + r * 64 + tid] = Wf1[r * 64 + tid];
    if (tid < 32) sW[O_bf1 + tid] = bf1[tid];
#pragma unroll
    for (int r = 0; r < 8; ++r) sW[O_Wf2 + r * 64 + tid] = Wf2[r * 64 + tid];
#pragma unroll
    for (int r = 0; r < 8; ++r) sW[O_Wh1 + r * 64 + tid] = Wh1[r * 64 + tid];
    if (tid < 32) sW[O_bh1 + tid] = bh1[tid];
#pragma unroll
    for (int r = 0; r < 4; ++r) sW[O_Wh2 + r * 64 + tid] = Wh2[r * 64 + tid];
#pragma unroll
    for (int r = 0; r < 8; ++r) sW[O_WT1 + r * 64 + tid] = WT1[r * 64 + tid];
    if (tid < 32) sW[O_bT1 + tid] = bT1[tid];
#pragma unroll
    for (int r = 0; r < 8; ++r) sW[O_WT2 + r * 64 + tid] = WT2[r * 64 + tid];
#pragma unroll
    for (int r = 0; r < 8; ++r) sW[O_Wtau1 + r * 64 + tid] = Wtau1[r * 64 + tid];
    if (tid < 32) sW[O_btau1 + tid] = btau1[tid];
#pragma unroll
    for (int r = 0; r < 8; ++r) sW[O_Wtau2 + r * 64 + tid] = Wtau2[r * 64 + tid];
#pragma unroll
    for (int r = 0; r < 12; ++r) sW[O_Wpsi1 + r * 64 + tid] = Wpsi1[r * 64 + tid];
    if (tid < 32) sW[O_bpsi1 + tid] = bpsi1[tid];
#pragma unroll
    for (int r = 0; r < 8; ++r) sW[O_Wpsi2 + r * 64 + tid] = Wpsi2[r * 64 + tid];
#pragma unroll
    for (int r = 0; r < 4; ++r) sW[O_WP + r * 64 + tid] = WP[r * 64 + tid];
  }
  __syncthreads();

  const float* sWf1 = sW + O_Wf1;
  const float* sbf1 = sW + O_bf1;
  const float* sWf2 = sW + O_Wf2;
  const float* sWh1 = sW + O_Wh1;
  const float* sbh1 = sW + O_bh1;
  const float* sWh2 = sW + O_Wh2;
  const float* sWT1 = sW + O_WT1;
  const float* sbT1 = sW + O_bT1;
  const float* sWT2 = sW + O_WT2;
  const float* sWtau1 = sW + O_Wtau1;
  const float* sbtau1 = sW + O_btau1;
  const float* sWtau2 = sW + O_Wtau2;
  const float* sWpsi1 = sW + O_Wpsi1;
  const float* sbpsi1 = sW + O_bpsi1;
  const float* sWpsi2 = sW + O_Wpsi2;
  const float* sWP = sW + O_WP;

  const int sidx = blockIdx.x * 64 + tid;

  // ---- load sample (coalesced float4) ----
  float x[DN], e[DNZ];
  {
    const float4* xp = reinterpret_cast<const float4*>(x_batch + (size_t)sidx * DN);
    const float4* ep = reinterpret_cast<const float4*>(e_batch + (size_t)sidx * DNZ);
#pragma unroll
    for (int q = 0; q < 4; ++q) {
      float4 vx = xp[q], ve = ep[q];
      x[4 * q + 0] = vx.x; x[4 * q + 1] = vx.y; x[4 * q + 2] = vx.z; x[4 * q + 3] = vx.w;
      e[4 * q + 0] = ve.x; e[4 * q + 1] = ve.y; e[4 * q + 2] = ve.z; e[4 * q + 3] = ve.w;
    }
  }

  float t32[DH];

  // ---- z = T(x) + e  (z held in a 16-vec, then consumed immediately) ----
  float xh[DN];
  {
    mv<DH, DN>(sWT1, x, t32);
#pragma unroll
    for (int k = 0; k < DH; ++k) t32[k] = ftanh(t32[k] + sbT1[k]);
    float z[DNZ];
    mv<DNZ, DH>(sWT2, t32, z);
#pragma unroll
    for (int j = 0; j < DNZ; ++j) z[j] += e[j];

    // ---- x_hat = tau(z) ----
    mv<DH, DNZ>(sWtau1, z, t32);
#pragma unroll
    for (int k = 0; k < DH; ++k) t32[k] = ftanh(t32[k] + sbtau1[k]);
    mv<DN, DH>(sWtau2, t32, xh);
  }
  // x becomes diff
#pragma unroll
  for (int n = 0; n < DN; ++n) x[n] -= xh[n];

  // ---- h stage at xh: th -> yh, dth ----
  float yh[DOUT];
  {
    float th[DH];
    mv<DH, DN>(sWh1, xh, th);
#pragma unroll
    for (int k = 0; k < DH; ++k) th[k] = ftanh(th[k] + sbh1[k]);
    mv<DOUT, DH>(sWh2, th, yh);
#pragma unroll
    for (int k = 0; k < DH; ++k) th[k] = 1.f - th[k] * th[k];  // dth

    // ---- term1 = P_inv @ (Jh^T @ ((Jh @ diff) * RINV)), consumes diff(=x) ----
    mv<DH, DN>(sWh1, x, t32);
#pragma unroll
    for (int k = 0; k < DH; ++k) t32[k] *= th[k];
    float w8[DOUT];
    mv<DOUT, DH>(sWh2, t32, w8);
#pragma unroll
    for (int o = 0; o < DOUT; ++o) w8[o] *= RINV;
    // t32 = dth ∘ (Wh2^T @ w8)
#pragma unroll
    for (int k = 0; k < DH; ++k) {
      float a = 0.f;
#pragma unroll
      for (int o = 0; o < DOUT; ++o) a = fmaf(sWh2[o * DH + k], w8[o], a);
      t32[k] = a * th[k];
    }
    // x = u = Wh1^T @ t32   (overwrite diff)
#pragma unroll
    for (int n = 0; n < DN; ++n) {
      float a = 0.f;
#pragma unroll
      for (int k = 0; k < DH; ++k) a = fmaf(sWh1[k * DN + n], t32[k], a);
      x[n] = a;
    }
    // s = tanh(WP @ xh); x = term1 = u + s*(s·u)
    float sv[DN];
    mv<DN, DN>(sWP, xh, sv);
#pragma unroll
    for (int n = 0; n < DN; ++n) sv[n] = ftanh(sv[n]);
    float sdot = 0.f;
#pragma unroll
    for (int n = 0; n < DN; ++n) sdot = fmaf(sv[n], x[n], sdot);
#pragma unroll
    for (int n = 0; n < DN; ++n) x[n] = fmaf(sv[n], sdot, x[n]);  // x = term1
  }

  // ---- Tx = T(xh) ----
  float Tx[DNZ];
  mv<DH, DN>(sWT1, xh, t32);
#pragma unroll
  for (int k = 0; k < DH; ++k) t32[k] = ftanh(t32[k] + sbT1[k]);
  mv<DNZ, DH>(sWT2, t32, Tx);

  // ---- psi stage: phi, dtp (in tp) ----
  float phi[DNZ];
  float tp[DH];
#pragma unroll
  for (int k = 0; k < DH; ++k) {
    float a = sbpsi1[k];
#pragma unroll
    for (int j = 0; j < DNZ; ++j) a = fmaf(sWpsi1[k * (DNZ + DOUT) + j], Tx[j], a);
#pragma unroll
    for (int o = 0; o < DOUT; ++o) a = fmaf(sWpsi1[k * (DNZ + DOUT) + DNZ + o], yh[o], a);
    tp[k] = ftanh(a);
  }
  mv<DNZ, DH>(sWpsi2, tp, phi);
#pragma unroll
  for (int k = 0; k < DH; ++k) tp[k] = 1.f - tp[k] * tp[k];  // dtp; yh dead

  // ---- jphi_e = Wpsi2 @ (dtp ∘ (Wpsi1[:, :NZ] @ e)) ----
  float jphi_e[DNZ];
#pragma unroll
  for (int k = 0; k < DH; ++k) {
    float a = 0.f;
#pragma unroll
    for (int j = 0; j < DNZ; ++j) a = fmaf(sWpsi1[k * (DNZ + DOUT) + j], e[j], a);
    t32[k] = tp[k] * a;
  }
  mv<DNZ, DH>(sWpsi2, t32, jphi_e);
  // tp dead

  // ---- tau at Tx: dtt (in tt), Htau term and Jtau@e ----
  float t2e[DN], jte[DN], tt[DH];
  {
    mv<DH, DNZ>(sWtau1, Tx, tt);
#pragma unroll
    for (int k = 0; k < DH; ++k) tt[k] = ftanh(tt[k] + sbtau1[k]);
    // Tx dead
    float wphi[DH];
    mv<DH, DNZ>(sWtau1, phi, wphi);  // phi dead after
    float v1[DH];
    mv<DH, DNZ>(sWtau1, e, v1);      // e dead after
#pragma unroll
    for (int k = 0; k < DH; ++k) {
      float t = tt[k];
      float d = 1.f - t * t;
      float c = -2.f * t * d * wphi[k];
      wphi[k] = c * v1[k];   // cvec
      v1[k] = d * v1[k];     // dv1
      tt[k] = d;             // dtt
    }
    mv<DN, DH>(sWtau2, wphi, t2e);  // Htau-term @ e
    mv<DN, DH>(sWtau2, v1, jte);    // Jtau @ e
  }

  // ---- t2e += Jtau @ jphi_e ----
  {
    mv<DH, DNZ>(sWtau1, jphi_e, t32);
#pragma unroll
    for (int k = 0; k < DH; ++k) t32[k] *= tt[k];
    float tmp16[DN];
    mv<DN, DH>(sWtau2, t32, tmp16);
#pragma unroll
    for (int n = 0; n < DN; ++n) t2e[n] += tmp16[n];
  }
  // tt, jphi_e dead

  // ---- t2e -= Jf @ jte ----
  {
    mv<DH, DN>(sWf1, xh, t32);  // pre-activation of f
    float g[DH];
    mv<DH, DN>(sWf1, jte, g);
#pragma unroll
    for (int k = 0; k < DH; ++k) {
      float t = ftanh(t32[k] + sbf1[k]);
      g[k] *= (1.f - t * t);
    }
    float tmp16[DN];
    mv<DN, DH>(sWf2, g, tmp16);
#pragma unroll
    for (int n = 0; n < DN; ++n) t2e[n] -= tmp16[n];
  }
  // xh, jte dead

  // ---- loss = ||term1 - term2@e|| ----
  float ss = 0.f;
#pragma unroll
  for (int n = 0; n < DN; ++n) {
    float r = x[n] - t2e[n];
    ss = fmaf(r, r, ss);
  }
  float loss = sqrtf(ss);

  // ---- wave(=block) reduction + one atomic per block ----
#pragma unroll
  for (int off = 32; off >= 1; off >>= 1) loss += __shfl_down(loss, off);
  if (tid == 0) atomicAdd(out, loss * (1.0f / (float)DB));
}

extern "C" void kernel_launch(void* const* d_in, const int* in_sizes, int n_in,
                              void* d_out, int out_size, void* d_ws, size_t ws_size,
                              hipStream_t stream) {
  const float* x_batch = (const float*)d_in[0];
  const float* e_batch = (const float*)d_in[1];
  const float* Wf1 = (const float*)d_in[2];
  const float* bf1 = (const float*)d_in[3];
  const float* Wf2 = (const float*)d_in[4];
  const float* Wh1 = (const float*)d_in[5];
  const float* bh1 = (const float*)d_in[6];
  const float* Wh2 = (const float*)d_in[7];
  const float* WT1 = (const float*)d_in[8];
  const float* bT1 = (const float*)d_in[9];
  const float* WT2 = (const float*)d_in[10];
  const float* Wtau1 = (const float*)d_in[11];
  const float* btau1 = (const float*)d_in[12];
  const float* Wtau2 = (const float*)d_in[13];
  const float* Wpsi1 = (const float*)d_in[14];
  const float* bpsi1 = (const float*)d_in[15];
  const float* Wpsi2 = (const float*)d_in[16];
  const float* WP = (const float*)d_in[17];

  hipMemsetAsync(d_out, 0, sizeof(float), stream);
  loss_kernel<<<DB / 64, 64, 0, stream>>>(
      x_batch, e_batch, Wf1, bf1, Wf2, Wh1, bh1, Wh2, WT1, bT1, WT2,
      Wtau1, btau1, Wtau2, Wpsi1, bpsi1, Wpsi2, WP, (float*)d_out);
}

// Round 3
// 48.584 us; speedup vs baseline: 13.6923x; 4.0171x over previous
//
#include <hip/hip_runtime.h>
#include <math.h>

#define DN 16
#define DNZ 16
#define DOUT 8
#define DH 32
#define DB 16384
#define RINV 10.0f
#define DPSI 24  // NZ+OUT

// ---- LDS layout (floats). Second-layer weights stored TRANSPOSED ([k][m])
// so column access in the fused rank-1 updates is contiguous -> ds_read_b128.
#define O_WT1    0      // 32x16
#define O_WT2T   512    // 32x16
#define O_Wtau1  1024   // 32x16
#define O_Wtau2T 1536   // 32x16
#define O_Wh1    2048   // 32x16
#define O_Wh2T   2560   // 32x8
#define O_Wpsi1  2816   // 32x24
#define O_Wpsi2T 3584   // 32x16
#define O_Wf1    4096   // 32x16
#define O_Wf2T   4608   // 32x16
#define O_WP     5120   // 16x16
#define O_bT1    5376
#define O_btau1  5408
#define O_bh1    5440
#define O_bpsi1  5472
#define O_bf1    5504
#define LDS_FLOATS 5536

// tanh(x) = 1 - 2/(1+exp(2x))
__device__ __forceinline__ float ftanh(float v) {
  float ex = __builtin_amdgcn_exp2f(v * 2.885390081777926815f);
  float r = __builtin_amdgcn_rcpf(1.0f + ex);
  return fmaf(-2.0f, r, 1.0f);
}

__global__ __launch_bounds__(64, 1) void loss_kernel(
    const float* __restrict__ x_batch, const float* __restrict__ e_batch,
    const float* __restrict__ Wf1, const float* __restrict__ bf1, const float* __restrict__ Wf2,
    const float* __restrict__ Wh1, const float* __restrict__ bh1, const float* __restrict__ Wh2,
    const float* __restrict__ WT1, const float* __restrict__ bT1, const float* __restrict__ WT2,
    const float* __restrict__ Wtau1, const float* __restrict__ btau1, const float* __restrict__ Wtau2,
    const float* __restrict__ Wpsi1, const float* __restrict__ bpsi1, const float* __restrict__ Wpsi2,
    const float* __restrict__ WP,
    float* __restrict__ out) {
  __shared__ float sW[LDS_FLOATS];
  const int tid = threadIdx.x;

  // ---- staging: first-layer weights row-major; second-layer transposed ----
  {
#pragma unroll
    for (int r = 0; r < 8; ++r) sW[O_WT1 + r * 64 + tid] = WT1[r * 64 + tid];
#pragma unroll
    for (int r = 0; r < 8; ++r) sW[O_Wtau1 + r * 64 + tid] = Wtau1[r * 64 + tid];
#pragma unroll
    for (int r = 0; r < 8; ++r) sW[O_Wh1 + r * 64 + tid] = Wh1[r * 64 + tid];
#pragma unroll
    for (int r = 0; r < 12; ++r) sW[O_Wpsi1 + r * 64 + tid] = Wpsi1[r * 64 + tid];
#pragma unroll
    for (int r = 0; r < 8; ++r) sW[O_Wf1 + r * 64 + tid] = Wf1[r * 64 + tid];
#pragma unroll
    for (int r = 0; r < 4; ++r) sW[O_WP + r * 64 + tid] = WP[r * 64 + tid];
    // transposed stores: global (M,32) -> LDS [k][m]
#pragma unroll
    for (int r = 0; r < 8; ++r) {
      int idx = r * 64 + tid; int j = idx >> 5, k = idx & 31;
      sW[O_WT2T + k * DNZ + j] = WT2[idx];
    }
#pragma unroll
    for (int r = 0; r < 8; ++r) {
      int idx = r * 64 + tid; int j = idx >> 5, k = idx & 31;
      sW[O_Wtau2T + k * DN + j] = Wtau2[idx];
    }
#pragma unroll
    for (int r = 0; r < 8; ++r) {
      int idx = r * 64 + tid; int j = idx >> 5, k = idx & 31;
      sW[O_Wpsi2T + k * DNZ + j] = Wpsi2[idx];
    }
#pragma unroll
    for (int r = 0; r < 8; ++r) {
      int idx = r * 64 + tid; int j = idx >> 5, k = idx & 31;
      sW[O_Wf2T + k * DN + j] = Wf2[idx];
    }
#pragma unroll
    for (int r = 0; r < 4; ++r) {
      int idx = r * 64 + tid; int o = idx >> 5, k = idx & 31;
      sW[O_Wh2T + k * DOUT + o] = Wh2[idx];
    }
    if (tid < 32) {
      sW[O_bT1 + tid] = bT1[tid];
      sW[O_btau1 + tid] = btau1[tid];
      sW[O_bh1 + tid] = bh1[tid];
      sW[O_bpsi1 + tid] = bpsi1[tid];
      sW[O_bf1 + tid] = bf1[tid];
    }
  }
  __syncthreads();

  const int sidx = blockIdx.x * 64 + tid;

  // ---- load sample ----
  float x[DN], e[DNZ];
  {
    const float4* xp = reinterpret_cast<const float4*>(x_batch + (size_t)sidx * DN);
    const float4* ep = reinterpret_cast<const float4*>(e_batch + (size_t)sidx * DNZ);
#pragma unroll
    for (int q = 0; q < 4; ++q) {
      float4 vx = xp[q], ve = ep[q];
      x[4 * q + 0] = vx.x; x[4 * q + 1] = vx.y; x[4 * q + 2] = vx.z; x[4 * q + 3] = vx.w;
      e[4 * q + 0] = ve.x; e[4 * q + 1] = ve.y; e[4 * q + 2] = ve.z; e[4 * q + 3] = ve.w;
    }
  }

  // ---- A: z = T(x) + e  (column-wise, no hidden vector) ----
  float z[DNZ];
#pragma unroll
  for (int j = 0; j < DNZ; ++j) z[j] = e[j];
#pragma unroll 2
  for (int k = 0; k < DH; ++k) {
    const float* Wr = sW + O_WT1 + k * DN;
    float a = sW[O_bT1 + k];
#pragma unroll
    for (int j = 0; j < DN; ++j) a = fmaf(Wr[j], x[j], a);
    float t = ftanh(a);
    const float* Ct = sW + O_WT2T + k * DNZ;
#pragma unroll
    for (int j = 0; j < DNZ; ++j) z[j] = fmaf(Ct[j], t, z[j]);
  }

  // ---- B: xh = tau(z) ----
  float xh[DN];
#pragma unroll
  for (int n = 0; n < DN; ++n) xh[n] = 0.f;
#pragma unroll 2
  for (int k = 0; k < DH; ++k) {
    const float* Wr = sW + O_Wtau1 + k * DNZ;
    float a = sW[O_btau1 + k];
#pragma unroll
    for (int j = 0; j < DNZ; ++j) a = fmaf(Wr[j], z[j], a);
    float t = ftanh(a);
    const float* Ct = sW + O_Wtau2T + k * DN;
#pragma unroll
    for (int n = 0; n < DN; ++n) xh[n] = fmaf(Ct[n], t, xh[n]);
  }
  // z dead; x becomes diff
#pragma unroll
  for (int n = 0; n < DN; ++n) x[n] -= xh[n];

  // ---- C: yh + dth ----
  float yh[DOUT];
#pragma unroll
  for (int o = 0; o < DOUT; ++o) yh[o] = 0.f;
  float dth[DH];
#pragma unroll 2
  for (int k = 0; k < DH; ++k) {
    const float* Wr = sW + O_Wh1 + k * DN;
    float a = sW[O_bh1 + k];
#pragma unroll
    for (int n = 0; n < DN; ++n) a = fmaf(Wr[n], xh[n], a);
    float t = ftanh(a);
    dth[k] = 1.f - t * t;
    const float* Ct = sW + O_Wh2T + k * DOUT;
#pragma unroll
    for (int o = 0; o < DOUT; ++o) yh[o] = fmaf(Ct[o], t, yh[o]);
  }

  // ---- D: w8 = RINV * Wh2 @ (dth ∘ (Wh1 @ diff)) ----
  float w8[DOUT];
#pragma unroll
  for (int o = 0; o < DOUT; ++o) w8[o] = 0.f;
#pragma unroll 2
  for (int k = 0; k < DH; ++k) {
    const float* Wr = sW + O_Wh1 + k * DN;
    float a = 0.f;
#pragma unroll
    for (int n = 0; n < DN; ++n) a = fmaf(Wr[n], x[n], a);
    float g = a * dth[k];
    const float* Ct = sW + O_Wh2T + k * DOUT;
#pragma unroll
    for (int o = 0; o < DOUT; ++o) w8[o] = fmaf(Ct[o], g, w8[o]);
  }
#pragma unroll
  for (int o = 0; o < DOUT; ++o) w8[o] *= RINV;
  // x(diff) dead

  // ---- E: u = Wh1^T @ (dth ∘ (Wh2^T @ w8)) ----
  float u[DN];
#pragma unroll
  for (int n = 0; n < DN; ++n) u[n] = 0.f;
#pragma unroll 2
  for (int k = 0; k < DH; ++k) {
    const float* Ct = sW + O_Wh2T + k * DOUT;
    float a = 0.f;
#pragma unroll
    for (int o = 0; o < DOUT; ++o) a = fmaf(Ct[o], w8[o], a);
    float g = a * dth[k];
    const float* Wr = sW + O_Wh1 + k * DN;
#pragma unroll
    for (int n = 0; n < DN; ++n) u[n] = fmaf(Wr[n], g, u[n]);
  }
  // dth, w8 dead

  // ---- F: s = tanh(WP@xh); u = term1 = u + s*(s·u) ----
  {
    float sv[DN];
#pragma unroll 4
    for (int n = 0; n < DN; ++n) {
      const float* Wr = sW + O_WP + n * DN;
      float a = 0.f;
#pragma unroll
      for (int j = 0; j < DN; ++j) a = fmaf(Wr[j], xh[j], a);
      sv[n] = ftanh(a);
    }
    float sdot = 0.f;
#pragma unroll
    for (int n = 0; n < DN; ++n) sdot = fmaf(sv[n], u[n], sdot);
#pragma unroll
    for (int n = 0; n < DN; ++n) u[n] = fmaf(sv[n], sdot, u[n]);
  }

  // ---- G: Tx = T(xh) ----
  float Tx[DNZ];
#pragma unroll
  for (int j = 0; j < DNZ; ++j) Tx[j] = 0.f;
#pragma unroll 2
  for (int k = 0; k < DH; ++k) {
    const float* Wr = sW + O_WT1 + k * DN;
    float a = sW[O_bT1 + k];
#pragma unroll
    for (int n = 0; n < DN; ++n) a = fmaf(Wr[n], xh[n], a);
    float t = ftanh(a);
    const float* Ct = sW + O_WT2T + k * DNZ;
#pragma unroll
    for (int j = 0; j < DNZ; ++j) Tx[j] = fmaf(Ct[j], t, Tx[j]);
  }

  // ---- H: phi = psi(Tx,yh); jphi = Jphi @ e  (single fused pass, no dtp array) ----
  float phi[DNZ], jph[DNZ];
#pragma unroll
  for (int j = 0; j < DNZ; ++j) { phi[j] = 0.f; jph[j] = 0.f; }
#pragma unroll 2
  for (int k = 0; k < DH; ++k) {
    const float* Wr = sW + O_Wpsi1 + k * DPSI;
    float a = sW[O_bpsi1 + k];
#pragma unroll
    for (int j = 0; j < DNZ; ++j) a = fmaf(Wr[j], Tx[j], a);
#pragma unroll
    for (int o = 0; o < DOUT; ++o) a = fmaf(Wr[DNZ + o], yh[o], a);
    float t = ftanh(a);
    float d = 1.f - t * t;
    float a2 = 0.f;
#pragma unroll
    for (int j = 0; j < DNZ; ++j) a2 = fmaf(Wr[j], e[j], a2);
    float g = d * a2;
    const float* Ct = sW + O_Wpsi2T + k * DNZ;
#pragma unroll
    for (int j = 0; j < DNZ; ++j) {
      phi[j] = fmaf(Ct[j], t, phi[j]);
      jph[j] = fmaf(Ct[j], g, jph[j]);
    }
  }
  // yh dead

  // ---- I: fused tau-at-Tx: t2e = Htau-term@e + Jtau@jph ; jte = Jtau@e ----
  float t2e[DN], jte[DN];
#pragma unroll
  for (int n = 0; n < DN; ++n) { t2e[n] = 0.f; jte[n] = 0.f; }
#pragma unroll 2
  for (int k = 0; k < DH; ++k) {
    const float* Wr = sW + O_Wtau1 + k * DNZ;
    float a = sW[O_btau1 + k];
    float wp = 0.f, v = 0.f, q = 0.f;
#pragma unroll
    for (int j = 0; j < DNZ; ++j) {
      float w = Wr[j];
      a = fmaf(w, Tx[j], a);
      wp = fmaf(w, phi[j], wp);
      v = fmaf(w, e[j], v);
      q = fmaf(w, jph[j], q);
    }
    float t = ftanh(a);
    float d = 1.f - t * t;
    float c = -2.f * t * d * wp;
    float g1 = fmaf(c, v, d * q);
    float g2 = d * v;
    const float* Ct = sW + O_Wtau2T + k * DN;
#pragma unroll
    for (int n = 0; n < DN; ++n) {
      t2e[n] = fmaf(Ct[n], g1, t2e[n]);
      jte[n] = fmaf(Ct[n], g2, jte[n]);
    }
  }
  // Tx, phi, jph, e dead

  // ---- J: t2e -= Jf @ jte ----
#pragma unroll 2
  for (int k = 0; k < DH; ++k) {
    const float* Wr = sW + O_Wf1 + k * DN;
    float a = sW[O_bf1 + k];
    float gj = 0.f;
#pragma unroll
    for (int n = 0; n < DN; ++n) {
      float w = Wr[n];
      a = fmaf(w, xh[n], a);
      gj = fmaf(w, jte[n], gj);
    }
    float t = ftanh(a);
    float g = (1.f - t * t) * gj;
    const float* Ct = sW + O_Wf2T + k * DN;
#pragma unroll
    for (int n = 0; n < DN; ++n) t2e[n] = fmaf(-Ct[n], g, t2e[n]);
  }

  // ---- K: loss = ||u - t2e|| ----
  float ss = 0.f;
#pragma unroll
  for (int n = 0; n < DN; ++n) {
    float r = u[n] - t2e[n];
    ss = fmaf(r, r, ss);
  }
  float loss = sqrtf(ss);

#pragma unroll
  for (int off = 32; off >= 1; off >>= 1) loss += __shfl_down(loss, off);
  if (tid == 0) atomicAdd(out, loss * (1.0f / (float)DB));
}

extern "C" void kernel_launch(void* const* d_in, const int* in_sizes, int n_in,
                              void* d_out, int out_size, void* d_ws, size_t ws_size,
                              hipStream_t stream) {
  const float* x_batch = (const float*)d_in[0];
  const float* e_batch = (const float*)d_in[1];
  const float* Wf1 = (const float*)d_in[2];
  const float* bf1 = (const float*)d_in[3];
  const float* Wf2 = (const float*)d_in[4];
  const float* Wh1 = (const float*)d_in[5];
  const float* bh1 = (const float*)d_in[6];
  const float* Wh2 = (const float*)d_in[7];
  const float* WT1 = (const float*)d_in[8];
  const float* bT1 = (const float*)d_in[9];
  const float* WT2 = (const float*)d_in[10];
  const float* Wtau1 = (const float*)d_in[11];
  const float* btau1 = (const float*)d_in[12];
  const float* Wtau2 = (const float*)d_in[13];
  const float* Wpsi1 = (const float*)d_in[14];
  const float* bpsi1 = (const float*)d_in[15];
  const float* Wpsi2 = (const float*)d_in[16];
  const float* WP = (const float*)d_in[17];

  hipMemsetAsync(d_out, 0, sizeof(float), stream);
  loss_kernel<<<DB / 64, 64, 0, stream>>>(
      x_batch, e_batch, Wf1, bf1, Wf2, Wh1, bh1, Wh2, WT1, bT1, WT2,
      Wtau1, btau1, Wtau2, Wpsi1, bpsi1, Wpsi2, WP, (float*)d_out);
}